// Round 9
// baseline (277.271 us; speedup 1.0000x reference)
//
#include <hip/hip_runtime.h>

// LabelLoss: out[b] = sum_{n,c<7} (pred[b,n,c] - gt[b,n,c])^2
// pred/gt: [256, 16384, 8] fp32.
// History: R1-R4 ~100 us (allocating reads cap ~10.5 GB/s/CU regardless of
// MLP/occupancy). R6 all-nt: ~75 us (~14 GB/s/CU). R7 pipeline-on-nt:
// neutral (rate cap, not latency). R8 mixed cached+nt: REGRESSED to ~87 us
// (paths contend, don't overlap). R9: switch ingest to global_load_lds DMA
// (returns to LDS, bypassing the TCP->VGPR return path entirely) -- the one
// read mechanism not yet tried; m97 sustained ~50 GB/s/CU through it.

typedef float vfloat4 __attribute__((ext_vector_type(4)));

#define THREADS 256
#define SPLIT 8                               // blocks per batch row
#define F4_PER_BATCH (16384 * 2)              // 32768 float4s per batch per stream
#define F4_PER_BLOCK (F4_PER_BATCH / SPLIT)   // 4096
#define ROUNDS 2                              // 4KB DMA rounds per stream per iter
#define F4_PER_ITER (THREADS * ROUNDS)        // 512 float4s per stream per iter
#define NITER (F4_PER_BLOCK / F4_PER_ITER)    // 8

__global__ __launch_bounds__(THREADS) void label_loss_kernel(
    const vfloat4* __restrict__ pred,
    const vfloat4* __restrict__ gt,
    float* __restrict__ out)
{
    // 8 KB per stream, 16 KB total: <=10 blocks/CU by LDS.
    __shared__ vfloat4 sP[F4_PER_ITER];
    __shared__ vfloat4 sG[F4_PER_ITER];

    const int b   = blockIdx.x / SPLIT;
    const int seg = blockIdx.x % SPLIT;
    const long base = (long)b * F4_PER_BATCH + (long)seg * F4_PER_BLOCK;

    const int tid   = threadIdx.x;
    const int wbase = tid & ~63;   // wave's first thread: DMA LDS base is
                                   // wave-uniform; HW adds lane*16.
    // Channel-7 mask: float4 index parity == tid&1 (all strides even):
    // lane-uniform, no divergence.
    const float m = (tid & 1) ? 0.0f : 1.0f;

    float acc0 = 0.0f, acc1 = 0.0f;

    #pragma unroll 1
    for (int it = 0; it < NITER; ++it) {
        const long g0 = base + (long)it * F4_PER_ITER;

        // Stage: direct global->LDS DMA, 16 B per lane per issue.
        #pragma unroll
        for (int r = 0; r < ROUNDS; ++r) {
            __builtin_amdgcn_global_load_lds(
                (const __attribute__((address_space(1))) void*)&pred[g0 + r * THREADS + tid],
                (__attribute__((address_space(3))) void*)&sP[r * THREADS + wbase],
                16, 0, 0);
            __builtin_amdgcn_global_load_lds(
                (const __attribute__((address_space(1))) void*)&gt[g0 + r * THREADS + tid],
                (__attribute__((address_space(3))) void*)&sG[r * THREADS + wbase],
                16, 0, 0);
        }
        __syncthreads();   // compiler emits s_waitcnt vmcnt(0) before barrier

        // Consume: consecutive lanes read consecutive float4s (2-way bank
        // aliasing = free, m136).
        {
            const vfloat4 d0 = sP[tid] - sG[tid];
            const vfloat4 d1 = sP[THREADS + tid] - sG[THREADS + tid];
            acc0 += d0.x * d0.x + d0.y * d0.y + d0.z * d0.z + m * (d0.w * d0.w);
            acc1 += d1.x * d1.x + d1.y * d1.y + d1.z * d1.z + m * (d1.w * d1.w);
        }
        __syncthreads();   // protect LDS before next stage overwrites
    }

    float v = acc0 + acc1;

    // 64-lane wave reduction
    #pragma unroll
    for (int off = 32; off > 0; off >>= 1)
        v += __shfl_down(v, off, 64);

    __shared__ float wsum[THREADS / 64];
    const int lane = tid & 63;
    const int wave = tid >> 6;
    if (lane == 0) wsum[wave] = v;
    __syncthreads();

    if (tid == 0) {
        atomicAdd(&out[b], wsum[0] + wsum[1] + wsum[2] + wsum[3]);
    }
}

extern "C" void kernel_launch(void* const* d_in, const int* in_sizes, int n_in,
                              void* d_out, int out_size, void* d_ws, size_t ws_size,
                              hipStream_t stream) {
    const vfloat4* pred = (const vfloat4*)d_in[0];
    const vfloat4* gt   = (const vfloat4*)d_in[1];
    float* out = (float*)d_out;

    // d_out is re-poisoned to 0xAA before every launch; we accumulate with
    // atomics, so zero it first (async memset is graph-capture safe).
    (void)hipMemsetAsync(d_out, 0, (size_t)out_size * sizeof(float), stream);

    const int n_blocks = 256 * SPLIT;  // 2048 blocks, 8 per CU
    label_loss_kernel<<<dim3(n_blocks), dim3(THREADS), 0, stream>>>(pred, gt, out);
}